// Round 7
// baseline (45.122 us; speedup 1.0000x reference)
//
#include <hip/hip_runtime.h>
#include <hip/hip_bf16.h>
#include <math.h>

typedef unsigned short u16;
typedef unsigned int u32;
typedef __attribute__((ext_vector_type(8))) short bf16x8;
typedef __attribute__((ext_vector_type(4))) float f32x4;

#define NB 128
#define ND 1024
#define NO 512
#define NK3 1536
#define EPSV 1e-5f
#define SCALEQK 0.04419417382415922f   // 1/sqrt(512)
#define LOG2E 1.4426950408889634f

static __device__ __forceinline__ float fast_exp2(float v) {
#if __has_builtin(__builtin_amdgcn_exp2f)
  return __builtin_amdgcn_exp2f(v);
#else
  return exp2f(v);
#endif
}
static __device__ __forceinline__ float fast_rcp(float v) {
#if __has_builtin(__builtin_amdgcn_rcpf)
  return __builtin_amdgcn_rcpf(v);
#else
  return 1.f / v;
#endif
}
static __device__ __forceinline__ u16 bf16_rtn(float f) {
  unsigned u = __float_as_uint(f);
  return (u16)((u + 0x7FFFu + ((u >> 16) & 1u)) >> 16);
}
static __device__ __forceinline__ void bf16_split(float f, u16& h, u16& l) {
  h = bf16_rtn(f);
  l = bf16_rtn(f - __uint_as_float(((unsigned)h) << 16));
}
static __device__ __forceinline__ float asinh_fast(float x) {
  const float ax = fabsf(x);
  const float s = sqrtf(fmaf(ax, ax, 1.f));
  return copysignf(__logf(ax + s), x);
}
static __device__ __forceinline__ float tanh_fast(float x) {
  return 1.f - 2.f * fast_rcp(fast_exp2(x * (2.f * LOG2E)) + 1.f);
}
static __device__ __forceinline__ float sig_fast(float x) {
  return fast_rcp(1.f + fast_exp2(-x * LOG2E));
}
static __device__ __forceinline__ float sinh_fast(float x) {
  const float z = fast_exp2(x * LOG2E);
  return 0.5f * (z - fast_rcp(z));
}

// =============== K1: attn (blocks 0..127) + gemmA full-K 32x32 tiles (blocks 128..191) ===============
// gemmA: per block one 32x32 output tile, ALL FOUR dot-products d1..d4 over K=1024.
// waves 0-3: d1 = x@k1, d2 = x@gt (quadrant w&3); waves 4-7: d3 = x@wa, d4 = asinh(x)@wa.
// Epilogue: d3/d4 -> LDS, waves 0-3 apply sigmoid/sinh, write featP (c1|c3 packed bf16 h|l).
__global__ __launch_bounds__(512) void k1_attn_gemmA(
    const float* __restrict__ x, const float* __restrict__ gt,
    const float* __restrict__ wt, const float* __restrict__ mt,
    const float* __restrict__ k1w, const float* __restrict__ b1,
    const float* __restrict__ embk, const float* __restrict__ embb,
    const float* __restrict__ ekd, float* __restrict__ Tfull,
    u32* __restrict__ featP) {
  __shared__ __align__(16) char smem[49152];
  const int bid = blockIdx.x;
  const int t = threadIdx.x;
  const int wv = t >> 6;

  if (bid < NB) {
    // ---------------- attention: T_b via tilted moments + order-5 Taylor ----------------
    float* xsh = (float*)smem;                        // 4 KB
    float(*red)[8] = (float(*)[8])(smem + 4096);      // 7x8
    float* bc = (float*)(smem + 4096 + 7 * 8 * 4);    // 9
    *(float2*)&xsh[t * 2] = *(const float2*)&x[bid * ND + t * 2];
    float s1, s3;
    {
      const float kk = embk[NO + t];
      s1 = embk[t] * kk;
      s3 = kk * embb[t];
    }
#pragma unroll
    for (int off = 32; off; off >>= 1) {
      s1 += __shfl_xor(s1, off);
      s3 += __shfl_xor(s3, off);
    }
    if ((t & 63) == 0) { red[0][wv] = s1; red[1][wv] = s3; }
    __syncthreads();
    if (t < 2) {
      float v = 0.f;
#pragma unroll
      for (int i = 0; i < 8; ++i) v += red[t][i];
      bc[t] = v;
    }
    __syncthreads();
    const float S1 = bc[0], S3 = bc[1];
    const float aL2 = SCALEQK * LOG2E * S3;
    const float dS1 = SCALEQK * S1;
    float mm[7];
#pragma unroll
    for (int k = 0; k < 7; ++k) mm[k] = 0.f;
#pragma unroll
    for (int j = 0; j < 2; ++j) {
      const float xe = xsh[t * 2 + j];
      float p = fast_exp2(aL2 * xe);
      mm[0] += p;
#pragma unroll
      for (int k = 1; k < 7; ++k) { p *= xe; mm[k] += p; }
    }
#pragma unroll
    for (int off = 32; off; off >>= 1)
#pragma unroll
      for (int k = 0; k < 7; ++k) mm[k] += __shfl_xor(mm[k], off);
    if ((t & 63) == 0)
#pragma unroll
      for (int k = 0; k < 7; ++k) red[k][wv] = mm[k];
    __syncthreads();
    if (t < 7) {
      float v = 0.f;
#pragma unroll
      for (int i = 0; i < 8; ++i) v += red[t][i];
      bc[2 + t] = v;
    }
    __syncthreads();
    const float invf[6] = {1.f, 1.f, 0.5f, 1.6666667e-1f, 4.1666668e-2f, 8.3333333e-3f};
    float cn[6], cd[6];
#pragma unroll
    for (int k = 0; k < 6; ++k) {
      cn[k] = bc[3 + k] * invf[k];
      cd[k] = bc[2 + k] * invf[k];
    }
    float Ta = 0.f;
#pragma unroll
    for (int j = 0; j < 2; ++j) {
      const int d = t * 2 + j;
      const float del = dS1 * xsh[d];
      float num = cn[5], den = cd[5];
#pragma unroll
      for (int k = 4; k >= 0; --k) {
        num = fmaf(num, del, cn[k]);
        den = fmaf(den, del, cd[k]);
      }
      Ta = fmaf(ekd[d], num / den, Ta);
    }
#pragma unroll
    for (int off = 32; off; off >>= 1) Ta += __shfl_xor(Ta, off);
    __syncthreads();
    if ((t & 63) == 0) red[0][wv] = Ta;
    __syncthreads();
    if (t == 0) {
      float v = 0.f;
#pragma unroll
      for (int i = 0; i < 8; ++i) v += red[0][i];
      Tfull[bid] = v;  // plain store; kernel boundary gives coherence
    }
    return;
  }

  // ---------------- gemmA: 64 blocks, 32x32 tile, full K ----------------
  u16* XH = (u16*)smem;                    // [32][64] swizzled, 4 KB
  u16* XL = (u16*)(smem + 4096);
  u16* AXH = (u16*)(smem + 8192);
  u16* AXL = (u16*)(smem + 12288);
  u16* BK1H = (u16*)(smem + 16384);        // [32 col][64 k] swizzled, 4 KB each
  u16* BK1L = (u16*)(smem + 20480);
  u16* BGTH = (u16*)(smem + 24576);
  u16* BGTL = (u16*)(smem + 28672);
  u16* BWAH = (u16*)(smem + 32768);
  u16* BWAL = (u16*)(smem + 36864);
  float* D3 = (float*)(smem + 40960);      // [32][32] 4 KB
  float* D4 = (float*)(smem + 45056);

  const int b2 = bid - NB;
  const int r0 = (b2 >> 4) * 32;           // row tile (b)
  const int o0 = (b2 & 15) * 32;           // col tile (o)
  const int lane = t & 63;
  const int q = wv & 3, hi = wv >> 2;
  const int qr = q >> 1, qc = q & 1;
  const f32x4 vz = {0.f, 0.f, 0.f, 0.f};
  f32x4 accA = vz, accB = vz;

  // staging indices
  const int arow = t >> 4, ak4 = (t & 15) * 4;     // A: 32 rows x 16 thr/row x 4 elems
  const int bkr = t >> 3, bc4 = (t & 7) * 4;       // B: 64 k-rows x 8 thr/row x 4 cols

  for (int c = 0; c < 16; ++c) {
    const int kc = c * 64;
    if (c) __syncthreads();
    // ---- stage A: x and asinh(x), rows r0..r0+31, k kc..kc+63 ----
    {
      const float4 v = *(const float4*)&x[(size_t)(r0 + arow) * ND + kc + ak4];
      const float e[4] = {v.x, v.y, v.z, v.w};
      u16 h[4], l[4], ah[4], al[4];
#pragma unroll
      for (int i = 0; i < 4; ++i) {
        bf16_split(e[i], h[i], l[i]);
        bf16_split(asinh_fast(e[i]), ah[i], al[i]);
      }
      const int byte = (arow * 128 + ak4 * 2) ^ ((arow & 7) << 4);
      *(uint2*)((char*)XH + byte) = make_uint2((u32)h[0] | ((u32)h[1] << 16), (u32)h[2] | ((u32)h[3] << 16));
      *(uint2*)((char*)XL + byte) = make_uint2((u32)l[0] | ((u32)l[1] << 16), (u32)l[2] | ((u32)l[3] << 16));
      *(uint2*)((char*)AXH + byte) = make_uint2((u32)ah[0] | ((u32)ah[1] << 16), (u32)ah[2] | ((u32)ah[3] << 16));
      *(uint2*)((char*)AXL + byte) = make_uint2((u32)al[0] | ((u32)al[1] << 16), (u32)al[2] | ((u32)al[3] << 16));
    }
    // ---- stage B: k1, gt, wa ([col][k] transposed, swizzled) ----
    {
      const size_t gidx = (size_t)(kc + bkr) * NO + o0 + bc4;
      const float4 wk1 = *(const float4*)&k1w[gidx];
      const float4 wgt = *(const float4*)&gt[gidx];
      const float4 wwt = *(const float4*)&wt[gidx];
      const float4 wmt = *(const float4*)&mt[gidx];
      const float ek1[4] = {wk1.x, wk1.y, wk1.z, wk1.w};
      const float egt[4] = {wgt.x, wgt.y, wgt.z, wgt.w};
      const float ewt[4] = {wwt.x, wwt.y, wwt.z, wwt.w};
      const float emt[4] = {wmt.x, wmt.y, wmt.z, wmt.w};
#pragma unroll
      for (int j = 0; j < 4; ++j) {
        const int col = bc4 + j;
        const int byte = (col * 128 + bkr * 2) ^ ((col & 7) << 4);
        u16 h, l;
        bf16_split(ek1[j], h, l);
        *(u16*)((char*)BK1H + byte) = h; *(u16*)((char*)BK1L + byte) = l;
        bf16_split(egt[j], h, l);
        *(u16*)((char*)BGTH + byte) = h; *(u16*)((char*)BGTL + byte) = l;
        bf16_split(tanh_fast(ewt[j]) * sig_fast(emt[j]), h, l);
        *(u16*)((char*)BWAH + byte) = h; *(u16*)((char*)BWAL + byte) = l;
      }
    }
    __syncthreads();
    // ---- compute: 2 k-steps of 32 ----
#pragma unroll
    for (int ks2 = 0; ks2 < 2; ++ks2) {
      const int kbyte = ks2 * 64 + (lane >> 4) * 16;
      const int fr = qr * 16 + (lane & 15);
      const int abyte = (fr * 128 + kbyte) ^ ((fr & 7) << 4);
      const int fcol = qc * 16 + (lane & 15);
      const int bbyte = (fcol * 128 + kbyte) ^ ((fcol & 7) << 4);
      if (hi == 0) {
        const bf16x8 xh = *(const bf16x8*)((const char*)XH + abyte);
        const bf16x8 xl = *(const bf16x8*)((const char*)XL + abyte);
        const bf16x8 b1h = *(const bf16x8*)((const char*)BK1H + bbyte);
        const bf16x8 b1l = *(const bf16x8*)((const char*)BK1L + bbyte);
        const bf16x8 b2h = *(const bf16x8*)((const char*)BGTH + bbyte);
        const bf16x8 b2l = *(const bf16x8*)((const char*)BGTL + bbyte);
        accA = __builtin_amdgcn_mfma_f32_16x16x32_bf16(xh, b1h, accA, 0, 0, 0);
        accA = __builtin_amdgcn_mfma_f32_16x16x32_bf16(xh, b1l, accA, 0, 0, 0);
        accA = __builtin_amdgcn_mfma_f32_16x16x32_bf16(xl, b1h, accA, 0, 0, 0);
        accB = __builtin_amdgcn_mfma_f32_16x16x32_bf16(xh, b2h, accB, 0, 0, 0);
        accB = __builtin_amdgcn_mfma_f32_16x16x32_bf16(xh, b2l, accB, 0, 0, 0);
        accB = __builtin_amdgcn_mfma_f32_16x16x32_bf16(xl, b2h, accB, 0, 0, 0);
      } else {
        const bf16x8 xh = *(const bf16x8*)((const char*)XH + abyte);
        const bf16x8 xl = *(const bf16x8*)((const char*)XL + abyte);
        const bf16x8 axh = *(const bf16x8*)((const char*)AXH + abyte);
        const bf16x8 axl = *(const bf16x8*)((const char*)AXL + abyte);
        const bf16x8 bwh = *(const bf16x8*)((const char*)BWAH + bbyte);
        const bf16x8 bwl = *(const bf16x8*)((const char*)BWAL + bbyte);
        accA = __builtin_amdgcn_mfma_f32_16x16x32_bf16(xh, bwh, accA, 0, 0, 0);
        accA = __builtin_amdgcn_mfma_f32_16x16x32_bf16(xh, bwl, accA, 0, 0, 0);
        accA = __builtin_amdgcn_mfma_f32_16x16x32_bf16(xl, bwh, accA, 0, 0, 0);
        accB = __builtin_amdgcn_mfma_f32_16x16x32_bf16(axh, bwh, accB, 0, 0, 0);
        accB = __builtin_amdgcn_mfma_f32_16x16x32_bf16(axh, bwl, accB, 0, 0, 0);
        accB = __builtin_amdgcn_mfma_f32_16x16x32_bf16(axl, bwh, accB, 0, 0, 0);
      }
    }
  }
  // ---- epilogue: exchange d3/d4, apply nonlinearities, write featP ----
  __syncthreads();
  if (hi == 1) {
#pragma unroll
    for (int r = 0; r < 4; ++r) {
      const int row = qr * 16 + (lane >> 4) * 4 + r;
      const int col = qc * 16 + (lane & 15);
      D3[row * 32 + col] = accA[r];
      D4[row * 32 + col] = accB[r];
    }
  }
  __syncthreads();
  if (hi == 0) {
#pragma unroll
    for (int r = 0; r < 4; ++r) {
      const int row = qr * 16 + (lane >> 4) * 4 + r;
      const int col = qc * 16 + (lane & 15);
      const float d1 = accA[r], d2 = accB[r];
      const float d3 = D3[row * 32 + col], d4 = D4[row * 32 + col];
      const float c1v = d1 + b1[o0 + col];
      const float gg = sig_fast(d2);
      const float mmv = sinh_fast(d4);
      const float c3v = fmaf(gg, d3 - mmv, mmv);
      u16 h, l;
      u32* fP = featP + (size_t)(r0 + row) * 1024;
      bf16_split(c1v, h, l);
      fP[o0 + col] = ((u32)h << 16) | l;
      bf16_split(c3v, h, l);
      fP[512 + o0 + col] = ((u32)h << 16) | l;
    }
  }
}

// =============== K2: gemmB feat[128,1536] @ k3[1536,512]; c4 synthesized in staging ===============
// 96 blocks (12 ksplit x 8 otile) x 512 threads; 128x64 tile, NCH=2; pB partials.
__global__ __launch_bounds__(512) void k2_gemmB(
    const u32* __restrict__ featP, const float* __restrict__ k3w,
    const float* __restrict__ embk, const float* __restrict__ embb,
    const float* __restrict__ ekd, const float* __restrict__ ng,
    const float* __restrict__ nbv, const float* __restrict__ Tfull,
    float* __restrict__ pB) {
  __shared__ __align__(16) char smem[50176];
  u16* AshH = (u16*)smem;                  // [128][64] swizzled, 16 KB
  u16* AshL = (u16*)(smem + 16384);
  u16* BshH = (u16*)(smem + 32768);        // [64 col][64 k] swizzled, 8 KB
  u16* BshL = (u16*)(smem + 40960);
  float* Ts = (float*)(smem + 49152);      // [128] T, then [128] rs
  float* Rs = Ts + 128;
  __shared__ float red[6][8];
  __shared__ float bcs[6];

  const int t = threadIdx.x;
  const int wv = t >> 6;
  const int lane = t & 63;
  const int wr = wv & 3, wc = wv >> 2;
  const int ks = blockIdx.x >> 3, ot = blockIdx.x & 7;
  const int o0 = ot * 64, k0 = ks * 128;

  // ---- per-block c4 constants: vk/vb moments + E ----
  {
    const float vk = embk[2 * NO + t], vb = embb[2 * NO + t];
    float svk = vk, svb = vb, svk2 = vk * vk, svkvb = vk * vb, svb2 = vb * vb;
    float se = ekd[t] + ekd[t + 512];
#pragma unroll
    for (int off = 32; off; off >>= 1) {
      svk += __shfl_xor(svk, off); svb += __shfl_xor(svb, off);
      svk2 += __shfl_xor(svk2, off); svkvb += __shfl_xor(svkvb, off);
      svb2 += __shfl_xor(svb2, off); se += __shfl_xor(se, off);
    }
    if ((t & 63) == 0) {
      red[0][wv] = svk; red[1][wv] = svb; red[2][wv] = svk2;
      red[3][wv] = svkvb; red[4][wv] = svb2; red[5][wv] = se;
    }
    __syncthreads();
    if (t < 6) {
      float v = 0.f;
#pragma unroll
      for (int i = 0; i < 8; ++i) v += red[t][i];
      bcs[t] = v;
    }
    __syncthreads();
  }
  const float inv_o = 1.f / (float)NO;
  const float mvk = bcs[0] * inv_o, mvb = bcs[1] * inv_o;
  const float Mvk2 = bcs[2] * inv_o - mvk * mvk;
  const float Mvkvb = bcs[3] * inv_o - mvk * mvb;
  const float Mvb2 = bcs[4] * inv_o - mvb * mvb;
  const float E = bcs[5];
  if (t < NB) {
    const float T = Tfull[t];
    const float var = T * T * Mvk2 + 2.f * T * E * Mvkvb + E * E * Mvb2;
    Ts[t] = T;
    Rs[t] = rsqrtf(var + EPSV);
  }
  __syncthreads();

  const f32x4 vz = {0.f, 0.f, 0.f, 0.f};
  f32x4 acc[2][2];
  acc[0][0] = vz; acc[0][1] = vz; acc[1][0] = vz; acc[1][1] = vz;

  for (int c = 0; c < 2; ++c) {
    const int kc = k0 + c * 64;
    if (c) __syncthreads();
    // ---- stage A: 4 passes of 32 rows; feat cols or synthesized c4 ----
    {
      const int rowb = t >> 4;
      const int c4 = (t & 15) * 4;
#pragma unroll
      for (int pass = 0; pass < 4; ++pass) {
        const int row = pass * 32 + rowb;
        const int byte = (row * 128 + c4 * 2) ^ ((row & 7) << 4);
        if (kc < 1024) {
          const uint4 v = *(const uint4*)(featP + (size_t)row * 1024 + kc + c4);
          const u32 h0 = (v.x >> 16) | (v.y & 0xFFFF0000u);
          const u32 l0 = (v.x & 0xFFFFu) | (v.y << 16);
          const u32 h1 = (v.z >> 16) | (v.w & 0xFFFF0000u);
          const u32 l1 = (v.z & 0xFFFFu) | (v.w << 16);
          *(uint2*)((char*)AshH + byte) = make_uint2(h0, h1);
          *(uint2*)((char*)AshL + byte) = make_uint2(l0, l1);
        } else {
          const int o = kc + c4 - 1024;
          const float4 vkv = *(const float4*)&embk[2 * NO + o];
          const float4 vbv = *(const float4*)&embb[2 * NO + o];
          const float4 ngv = *(const float4*)&ng[o];
          const float4 nbvv = *(const float4*)&nbv[o];
          const float T = Ts[row], rs = Rs[row];
          const float vkc[4] = {vkv.x - mvk, vkv.y - mvk, vkv.z - mvk, vkv.w - mvk};
          const float vbc[4] = {vbv.x - mvb, vbv.y - mvb, vbv.z - mvb, vbv.w - mvb};
          const float ngs[4] = {ngv.x, ngv.y, ngv.z, ngv.w};
          const float nbs[4] = {nbvv.x, nbvv.y, nbvv.z, nbvv.w};
          u16 h[4], l[4];
#pragma unroll
          for (int j = 0; j < 4; ++j) {
            const float c4v = (T * vkc[j] + E * vbc[j]) * rs * ngs[j] + nbs[j];
            bf16_split(c4v, h[j], l[j]);
          }
          *(uint2*)((char*)AshH + byte) =
              make_uint2((u32)h[0] | ((u32)h[1] << 16), (u32)h[2] | ((u32)h[3] << 16));
          *(uint2*)((char*)AshL + byte) =
              make_uint2((u32)l[0] | ((u32)l[1] << 16), (u32)l[2] | ((u32)l[3] << 16));
        }
      }
    }
    // ---- stage B: k3 rows kc..kc+63, cols o0..o0+63 ----
    {
      const int kp = t >> 4, og = t & 15;
      const int gk = kc + kp * 2, go = o0 + og * 4;
      const float4 w0 = *(const float4*)&k3w[(size_t)gk * NO + go];
      const float4 w1 = *(const float4*)&k3w[(size_t)(gk + 1) * NO + go];
      const float e0[4] = {w0.x, w0.y, w0.z, w0.w};
      const float e1[4] = {w1.x, w1.y, w1.z, w1.w};
#pragma unroll
      for (int j = 0; j < 4; ++j) {
        u16 h0, l0, h1, l1;
        bf16_split(e0[j], h0, l0);
        bf16_split(e1[j], h1, l1);
        const int col = og * 4 + j;
        const int byte = (col * 128 + kp * 4) ^ ((col & 7) << 4);
        *(u32*)((char*)BshH + byte) = (u32)h0 | ((u32)h1 << 16);
        *(u32*)((char*)BshL + byte) = (u32)l0 | ((u32)l1 << 16);
      }
    }
    __syncthreads();
    // ---- compute ----
#pragma unroll
    for (int ks2 = 0; ks2 < 2; ++ks2) {
      const int kb = ((lane >> 4) * 16) + ks2 * 64;
      bf16x8 a_h[2], a_l[2], b_h[2], b_l[2];
#pragma unroll
      for (int m = 0; m < 2; ++m) {
        const int row = wr * 32 + m * 16 + (lane & 15);
        const int byte = (row * 128 + kb) ^ ((row & 7) << 4);
        a_h[m] = *(const bf16x8*)((const char*)AshH + byte);
        a_l[m] = *(const bf16x8*)((const char*)AshL + byte);
      }
#pragma unroll
      for (int n = 0; n < 2; ++n) {
        const int col = wc * 32 + n * 16 + (lane & 15);
        const int byte = (col * 128 + kb) ^ ((col & 7) << 4);
        b_h[n] = *(const bf16x8*)((const char*)BshH + byte);
        b_l[n] = *(const bf16x8*)((const char*)BshL + byte);
      }
#pragma unroll
      for (int m = 0; m < 2; ++m)
#pragma unroll
        for (int n = 0; n < 2; ++n) {
          acc[m][n] = __builtin_amdgcn_mfma_f32_16x16x32_bf16(a_h[m], b_h[n], acc[m][n], 0, 0, 0);
          acc[m][n] = __builtin_amdgcn_mfma_f32_16x16x32_bf16(a_h[m], b_l[n], acc[m][n], 0, 0, 0);
          acc[m][n] = __builtin_amdgcn_mfma_f32_16x16x32_bf16(a_l[m], b_h[n], acc[m][n], 0, 0, 0);
        }
    }
  }
  // ---- epilogue: plain partial stores ----
  float* outp = pB + (size_t)ks * (NB * NO);
#pragma unroll
  for (int m = 0; m < 2; ++m)
#pragma unroll
    for (int n = 0; n < 2; ++n) {
      const int col = o0 + wc * 32 + n * 16 + (lane & 15);
#pragma unroll
      for (int r = 0; r < 4; ++r) {
        const int row = wr * 32 + m * 16 + (lane >> 4) * 4 + r;
        outp[(size_t)row * NO + col] = acc[m][n][r];
      }
    }
}

// =============== K3: combineB -> out ===============
__global__ __launch_bounds__(512) void k3_combineB(
    const float* __restrict__ pB, const float* __restrict__ bias3,
    float* __restrict__ out) {
  const int p = blockIdx.x * 512 + threadIdx.x;
  const int o = p & 511;
  float s = bias3[o];
#pragma unroll
  for (int ks = 0; ks < 12; ++ks) s += pB[(size_t)ks * (NB * NO) + p];
  out[p] = s;
}

extern "C" void kernel_launch(void* const* d_in, const int* in_sizes, int n_in,
                              void* d_out, int out_size, void* d_ws, size_t ws_size,
                              hipStream_t stream) {
  const float* x    = (const float*)d_in[0];
  const float* gt   = (const float*)d_in[1];
  const float* wt   = (const float*)d_in[2];
  const float* mt   = (const float*)d_in[3];
  const float* k1   = (const float*)d_in[4];
  const float* b1   = (const float*)d_in[5];
  const float* k3   = (const float*)d_in[6];
  const float* b3   = (const float*)d_in[7];
  const float* embk = (const float*)d_in[8];
  const float* embb = (const float*)d_in[9];
  const float* ekd  = (const float*)d_in[10];
  const float* ng   = (const float*)d_in[11];
  const float* nb   = (const float*)d_in[12];

  char* wsb = (char*)d_ws;
  float* Tfull = (float*)wsb;                    // 512 B
  u32* featP = (u32*)(wsb + 4096);               // 128*1024*4 = 512 KB
  float* pB = (float*)(wsb + 4096 + (512u << 10));  // 12*128*512*4 = 3 MB
  float* out = (float*)d_out;

  hipLaunchKernelGGL(k1_attn_gemmA, dim3(192), dim3(512), 0, stream,
                     x, gt, wt, mt, k1, b1, embk, embb, ekd, Tfull, featP);
  hipLaunchKernelGGL(k2_gemmB, dim3(96), dim3(512), 0, stream,
                     featP, k3, embk, embb, ekd, ng, nb, Tfull, pB);
  hipLaunchKernelGGL(k3_combineB, dim3(128), dim3(512), 0, stream,
                     pB, b3, out);
}

// Round 8
// 33.794 us; speedup vs baseline: 1.3352x; 1.3352x over previous
//
#include <hip/hip_runtime.h>
#include <hip/hip_bf16.h>
#include <math.h>

typedef unsigned short u16;
typedef unsigned int u32;
typedef __attribute__((ext_vector_type(8))) short bf16x8;
typedef __attribute__((ext_vector_type(4))) float f32x4;

#define NB 128
#define ND 1024
#define NO 512
#define EPSV 1e-5f
#define SCALEQK 0.04419417382415922f   // 1/sqrt(512)
#define LOG2E 1.4426950408889634f

static __device__ __forceinline__ float fast_exp2(float v) {
#if __has_builtin(__builtin_amdgcn_exp2f)
  return __builtin_amdgcn_exp2f(v);
#else
  return exp2f(v);
#endif
}
static __device__ __forceinline__ float fast_rcp(float v) {
#if __has_builtin(__builtin_amdgcn_rcpf)
  return __builtin_amdgcn_rcpf(v);
#else
  return 1.f / v;
#endif
}
static __device__ __forceinline__ u16 bf16_rtn(float f) {
  unsigned u = __float_as_uint(f);
  return (u16)((u + 0x7FFFu + ((u >> 16) & 1u)) >> 16);
}
static __device__ __forceinline__ void bf16_split(float f, u16& h, u16& l) {
  h = bf16_rtn(f);
  l = bf16_rtn(f - __uint_as_float(((unsigned)h) << 16));
}
static __device__ __forceinline__ float asinh_fast(float x) {
  const float ax = fabsf(x);
  const float s = sqrtf(fmaf(ax, ax, 1.f));
  return copysignf(__logf(ax + s), x);
}
static __device__ __forceinline__ float tanh_fast(float x) {
  return 1.f - 2.f * fast_rcp(fast_exp2(x * (2.f * LOG2E)) + 1.f);
}
static __device__ __forceinline__ float sig_fast(float x) {
  return fast_rcp(1.f + fast_exp2(-x * LOG2E));
}
static __device__ __forceinline__ float sinh_fast(float x) {
  const float z = fast_exp2(x * LOG2E);
  return 0.5f * (z - fast_rcp(z));
}

// =============== shared MFMA GEMM tile: 128 rows x 64 cols, K-span 128 (2 chunks) ===============
// A always packed u32 (bf16 h<<16|l), row stride ND. B row stride NO.
// BPACKED: 0 = fp32 split inline, 1 = packed u32. ATOMIC: 0 = plain store, 1 = atomicAdd.
template <int BPACKED, int ATOMIC>
static __device__ __forceinline__ void gemm_128x64(
    const u32* __restrict__ AP, const float* __restrict__ Bf,
    const u32* __restrict__ BP, float* __restrict__ outp,
    int o0, int k0, char* smem) {
  u16* AshH = (u16*)smem;                // [128][64] swizzled, 16 KB
  u16* AshL = (u16*)(smem + 16384);
  u16* BshH = (u16*)(smem + 32768);      // [64 col][64 k] swizzled, 8 KB
  u16* BshL = (u16*)(smem + 40960);
  const int t = threadIdx.x;
  const int lane = t & 63;
  const int wr = (t >> 6) & 3;           // wave row-block 0..3
  const int wc = t >> 8;                 // wave col-block 0..1
  const f32x4 vz = {0.f, 0.f, 0.f, 0.f};
  f32x4 acc[2][2];
  acc[0][0] = vz; acc[0][1] = vz; acc[1][0] = vz; acc[1][1] = vz;

#pragma unroll
  for (int c = 0; c < 2; ++c) {
    const int kc = k0 + c * 64;
    if (c) __syncthreads();
    // ---- stage A: packed u32 loads, coalesced 16 lanes/row ----
    {
      const int rowb = t >> 4;
      const int e0 = (t & 15) * 4;
#pragma unroll
      for (int pass = 0; pass < 4; ++pass) {
        const int row = pass * 32 + rowb;
        const uint4 v = *(const uint4*)(AP + (size_t)row * ND + kc + e0);
        const u32 h0 = (v.x >> 16) | (v.y & 0xFFFF0000u);
        const u32 l0 = (v.x & 0xFFFFu) | (v.y << 16);
        const u32 h1 = (v.z >> 16) | (v.w & 0xFFFF0000u);
        const u32 l1 = (v.z & 0xFFFFu) | (v.w << 16);
        const int byte = (row * 128 + e0 * 2) ^ ((row & 7) << 4);
        *(uint2*)((char*)AshH + byte) = make_uint2(h0, h1);
        *(uint2*)((char*)AshL + byte) = make_uint2(l0, l1);
      }
    }
    // ---- stage B transposed [col][k] ----
    {
      const int kp = t >> 4, og = t & 15;
      const int gk = kc + kp * 2, go = o0 + og * 4;
      u32 hw[4], lw[4];
      if (BPACKED) {
        const uint4 p0 = *(const uint4*)(BP + (size_t)gk * NO + go);
        const uint4 p1 = *(const uint4*)(BP + (size_t)(gk + 1) * NO + go);
        const u32 a0[4] = {p0.x, p0.y, p0.z, p0.w};
        const u32 a1[4] = {p1.x, p1.y, p1.z, p1.w};
#pragma unroll
        for (int j = 0; j < 4; ++j) {
          hw[j] = (a0[j] >> 16) | (a1[j] & 0xFFFF0000u);
          lw[j] = (a0[j] & 0xFFFFu) | (a1[j] << 16);
        }
      } else {
        const float4 w0 = *(const float4*)&Bf[(size_t)gk * NO + go];
        const float4 w1 = *(const float4*)&Bf[(size_t)(gk + 1) * NO + go];
        const float e0v[4] = {w0.x, w0.y, w0.z, w0.w};
        const float e1v[4] = {w1.x, w1.y, w1.z, w1.w};
#pragma unroll
        for (int j = 0; j < 4; ++j) {
          u16 h0, l0, h1, l1;
          bf16_split(e0v[j], h0, l0);
          bf16_split(e1v[j], h1, l1);
          hw[j] = (u32)h0 | ((u32)h1 << 16);
          lw[j] = (u32)l0 | ((u32)l1 << 16);
        }
      }
#pragma unroll
      for (int j = 0; j < 4; ++j) {
        const int col = og * 4 + j;
        const int byte = (col * 128 + kp * 4) ^ ((col & 7) << 4);
        *(u32*)((char*)BshH + byte) = hw[j];
        *(u32*)((char*)BshL + byte) = lw[j];
      }
    }
    __syncthreads();
    // ---- compute: 2 k-steps of 32, bf16 h/l 3-pass ----
#pragma unroll
    for (int ks2 = 0; ks2 < 2; ++ks2) {
      const int kb = ((lane >> 4) * 16) + ks2 * 64;
      bf16x8 a_h[2], a_l[2], b_h[2], b_l[2];
#pragma unroll
      for (int m = 0; m < 2; ++m) {
        const int row = wr * 32 + m * 16 + (lane & 15);
        const int byte = (row * 128 + kb) ^ ((row & 7) << 4);
        a_h[m] = *(const bf16x8*)((const char*)AshH + byte);
        a_l[m] = *(const bf16x8*)((const char*)AshL + byte);
      }
#pragma unroll
      for (int n = 0; n < 2; ++n) {
        const int col = wc * 32 + n * 16 + (lane & 15);
        const int byte = (col * 128 + kb) ^ ((col & 7) << 4);
        b_h[n] = *(const bf16x8*)((const char*)BshH + byte);
        b_l[n] = *(const bf16x8*)((const char*)BshL + byte);
      }
#pragma unroll
      for (int m = 0; m < 2; ++m)
#pragma unroll
        for (int n = 0; n < 2; ++n) {
          acc[m][n] = __builtin_amdgcn_mfma_f32_16x16x32_bf16(a_h[m], b_h[n], acc[m][n], 0, 0, 0);
          acc[m][n] = __builtin_amdgcn_mfma_f32_16x16x32_bf16(a_h[m], b_l[n], acc[m][n], 0, 0, 0);
          acc[m][n] = __builtin_amdgcn_mfma_f32_16x16x32_bf16(a_l[m], b_h[n], acc[m][n], 0, 0, 0);
        }
    }
  }
  // ---- epilogue: C/D layout col=lane&15, row=(lane>>4)*4+reg ----
#pragma unroll
  for (int m = 0; m < 2; ++m)
#pragma unroll
    for (int n = 0; n < 2; ++n) {
      const int col = o0 + wc * 32 + n * 16 + (lane & 15);
#pragma unroll
      for (int r = 0; r < 4; ++r) {
        const int row = wr * 32 + m * 16 + (lane >> 4) * 4 + r;
        if (ATOMIC)
          atomicAdd(&outp[(size_t)row * NO + col], acc[m][n][r]);
        else
          outp[(size_t)row * NO + col] = acc[m][n][r];
      }
    }
}

// =============== K1: waP prep (0..63) | attn (64..191) | x prep (192..319) | UVW (320..327) ===============
__global__ __launch_bounds__(512) void k1_misc(
    const float* __restrict__ x, const float* __restrict__ wt,
    const float* __restrict__ mt, const float* __restrict__ embk,
    const float* __restrict__ embb, const float* __restrict__ ekd,
    const float* __restrict__ k3w, const float* __restrict__ ng,
    const float* __restrict__ nbv, float* __restrict__ Tfull,
    u32* __restrict__ xP, u32* __restrict__ axP, u32* __restrict__ waP,
    float* __restrict__ U, float* __restrict__ V, float* __restrict__ Wc) {
  __shared__ __align__(16) char smem[8192];
  const int bid = blockIdx.x;
  const int t = threadIdx.x;
  const int wv = t >> 6;

  if (bid < 64) {
    // ---- waP: wa = tanh(wt)*sigmoid(mt), packed bf16 h|l; rows 16*bid..+15 ----
    const int r0 = bid * 16;
#pragma unroll
    for (int rr = 0; rr < 16; ++rr) {
      const int idx = (r0 + rr) * NO + t;
      const float wa = tanh_fast(wt[idx]) * sig_fast(mt[idx]);
      u16 h, l;
      bf16_split(wa, h, l);
      waP[idx] = ((u32)h << 16) | l;
    }
    return;
  }
  if (bid < 192) {
    // ---- attention: T_b via tilted moments + order-5 Taylor ----
    const int b = bid - 64;
    float* xsh = (float*)smem;
    float(*red)[8] = (float(*)[8])(smem + 4096);
    float* bc = (float*)(smem + 4096 + 7 * 8 * 4);
    *(float2*)&xsh[t * 2] = *(const float2*)&x[b * ND + t * 2];
    float s1, s3;
    {
      const float kk = embk[NO + t];
      s1 = embk[t] * kk;
      s3 = kk * embb[t];
    }
#pragma unroll
    for (int off = 32; off; off >>= 1) {
      s1 += __shfl_xor(s1, off);
      s3 += __shfl_xor(s3, off);
    }
    if ((t & 63) == 0) { red[0][wv] = s1; red[1][wv] = s3; }
    __syncthreads();
    if (t < 2) {
      float v = 0.f;
#pragma unroll
      for (int i = 0; i < 8; ++i) v += red[t][i];
      bc[t] = v;
    }
    __syncthreads();
    const float S1 = bc[0], S3 = bc[1];
    const float aL2 = SCALEQK * LOG2E * S3;
    const float dS1 = SCALEQK * S1;
    float mm[7];
#pragma unroll
    for (int k = 0; k < 7; ++k) mm[k] = 0.f;
#pragma unroll
    for (int j = 0; j < 2; ++j) {
      const float xe = xsh[t * 2 + j];
      float p = fast_exp2(aL2 * xe);
      mm[0] += p;
#pragma unroll
      for (int k = 1; k < 7; ++k) { p *= xe; mm[k] += p; }
    }
#pragma unroll
    for (int off = 32; off; off >>= 1)
#pragma unroll
      for (int k = 0; k < 7; ++k) mm[k] += __shfl_xor(mm[k], off);
    if ((t & 63) == 0)
#pragma unroll
      for (int k = 0; k < 7; ++k) red[k][wv] = mm[k];
    __syncthreads();
    if (t < 7) {
      float v = 0.f;
#pragma unroll
      for (int i = 0; i < 8; ++i) v += red[t][i];
      bc[2 + t] = v;
    }
    __syncthreads();
    const float invf[6] = {1.f, 1.f, 0.5f, 1.6666667e-1f, 4.1666668e-2f, 8.3333333e-3f};
    float cn[6], cd[6];
#pragma unroll
    for (int k = 0; k < 6; ++k) {
      cn[k] = bc[3 + k] * invf[k];
      cd[k] = bc[2 + k] * invf[k];
    }
    float Ta = 0.f;
#pragma unroll
    for (int j = 0; j < 2; ++j) {
      const int d = t * 2 + j;
      const float del = dS1 * xsh[d];
      float num = cn[5], den = cd[5];
#pragma unroll
      for (int k = 4; k >= 0; --k) {
        num = fmaf(num, del, cn[k]);
        den = fmaf(den, del, cd[k]);
      }
      Ta = fmaf(ekd[d], num / den, Ta);
    }
#pragma unroll
    for (int off = 32; off; off >>= 1) Ta += __shfl_xor(Ta, off);
    __syncthreads();
    if ((t & 63) == 0) red[0][wv] = Ta;
    __syncthreads();
    if (t == 0) {
      float v = 0.f;
#pragma unroll
      for (int i = 0; i < 8; ++i) v += red[0][i];
      Tfull[b] = v;
    }
    return;
  }
  if (bid < 320) {
    // ---- x prep: packed bf16 h|l of x and asinh(x), one row per block ----
    const int r = bid - 192;
    const float2 v = *(const float2*)&x[r * ND + t * 2];
    u16 h0, l0, h1, l1, a0h, a0l, a1h, a1l;
    bf16_split(v.x, h0, l0);
    bf16_split(v.y, h1, l1);
    bf16_split(asinh_fast(v.x), a0h, a0l);
    bf16_split(asinh_fast(v.y), a1h, a1l);
    *(uint2*)&xP[r * ND + t * 2] =
        make_uint2(((u32)h0 << 16) | l0, ((u32)h1 << 16) | l1);
    *(uint2*)&axP[r * ND + t * 2] =
        make_uint2(((u32)a0h << 16) | a0l, ((u32)a1h << 16) | a1l);
    return;
  }
  // ---- UVW: U=u@K33, V=v@K33, Wc=nb@K33 where u=(vk-mvk)*ng, v=(vb-mvb)*ng ----
  {
    float(*lds)[64][3] = (float(*)[64][3])smem;  // 8*64*3 floats = 6 KB
    __shared__ float mred[2][8];
    __shared__ float mbc[2];
    float svk = embk[2 * NO + t], svb = embb[2 * NO + t];
#pragma unroll
    for (int off = 32; off; off >>= 1) {
      svk += __shfl_xor(svk, off);
      svb += __shfl_xor(svb, off);
    }
    if ((t & 63) == 0) { mred[0][wv] = svk; mred[1][wv] = svb; }
    __syncthreads();
    if (t < 2) {
      float s = 0.f;
#pragma unroll
      for (int i = 0; i < 8; ++i) s += mred[t][i];
      mbc[t] = s * (1.f / (float)NO);
    }
    __syncthreads();
    const float mvk = mbc[0], mvb = mbc[1];
    const int jbase = (bid - 320) * 64;
    const int j = jbase + (t & 63);
    const int oc = t >> 6;
    float au = 0.f, av = 0.f, aw = 0.f;
#pragma unroll 4
    for (int oo = 0; oo < 64; ++oo) {
      const int o = oc * 64 + oo;
      const float kj = k3w[(size_t)(2 * NO + o) * NO + j];
      const float g = ng[o];
      au = fmaf((embk[2 * NO + o] - mvk) * g, kj, au);
      av = fmaf((embb[2 * NO + o] - mvb) * g, kj, av);
      aw = fmaf(nbv[o], kj, aw);
    }
    lds[oc][t & 63][0] = au;
    lds[oc][t & 63][1] = av;
    lds[oc][t & 63][2] = aw;
    __syncthreads();
    if (t < 64) {
      float su = 0.f, sv = 0.f, sw = 0.f;
#pragma unroll
      for (int cch = 0; cch < 8; ++cch) {
        su += lds[cch][t][0];
        sv += lds[cch][t][1];
        sw += lds[cch][t][2];
      }
      U[jbase + t] = su;
      V[jbase + t] = sv;
      Wc[jbase + t] = sw;
    }
  }
}

// =============== K2: gemmA (256 blocks) + out-init/rank-2-c4 shadow block (1) ===============
__global__ __launch_bounds__(512) void k2_gemmA(
    const u32* __restrict__ xP, const u32* __restrict__ axP,
    const u32* __restrict__ waP, const float* __restrict__ k1w,
    const float* __restrict__ gt, const float* __restrict__ embk,
    const float* __restrict__ embb, const float* __restrict__ ekd,
    const float* __restrict__ Tfull, const float* __restrict__ U,
    const float* __restrict__ V, const float* __restrict__ Wc,
    const float* __restrict__ b3, float* __restrict__ pA,
    float* __restrict__ out) {
  __shared__ __align__(16) char smem[49152];
  const int bid = blockIdx.x;
  const int t = threadIdx.x;
  if (bid < 256) {
    // g x ksplit8 x otile8; tile 128x64, K-span 128
    const int g = bid >> 6, ks = (bid >> 3) & 7, ot = bid & 7;
    float* outp = pA + (size_t)(bid >> 3) * (NB * NO);  // slot g*8+ks
    const u32* AP = (g == 3) ? axP : xP;
    if (g == 0)
      gemm_128x64<0, 0>(AP, k1w, nullptr, outp, ot * 64, ks * 128, smem);
    else if (g == 1)
      gemm_128x64<0, 0>(AP, gt, nullptr, outp, ot * 64, ks * 128, smem);
    else
      gemm_128x64<1, 0>(AP, nullptr, waP, outp, ot * 64, ks * 128, smem);
    return;
  }
  // ---- shadow block: layernorm scalars + out init (bias + rank-2 c4@K33) ----
  __shared__ float red6[6][8];
  __shared__ float bc6[6];
  __shared__ float aSl[NB];
  __shared__ float cSl[NB];
  const int wv = t >> 6;
  {
    const float vk = embk[2 * NO + t], vb = embb[2 * NO + t];
    float svk = vk, svb = vb, svk2 = vk * vk, svkvb = vk * vb, svb2 = vb * vb;
    float se = ekd[t] + ekd[t + 512];
#pragma unroll
    for (int off = 32; off; off >>= 1) {
      svk += __shfl_xor(svk, off); svb += __shfl_xor(svb, off);
      svk2 += __shfl_xor(svk2, off); svkvb += __shfl_xor(svkvb, off);
      svb2 += __shfl_xor(svb2, off); se += __shfl_xor(se, off);
    }
    if ((t & 63) == 0) {
      red6[0][wv] = svk; red6[1][wv] = svb; red6[2][wv] = svk2;
      red6[3][wv] = svkvb; red6[4][wv] = svb2; red6[5][wv] = se;
    }
    __syncthreads();
    if (t < 6) {
      float s = 0.f;
#pragma unroll
      for (int i = 0; i < 8; ++i) s += red6[t][i];
      bc6[t] = s;
    }
    __syncthreads();
  }
  const float inv_o = 1.f / (float)NO;
  const float mvk = bc6[0] * inv_o, mvb = bc6[1] * inv_o;
  const float Mvk2 = bc6[2] * inv_o - mvk * mvk;
  const float Mvkvb = bc6[3] * inv_o - mvk * mvb;
  const float Mvb2 = bc6[4] * inv_o - mvb * mvb;
  const float E = bc6[5];
  if (t < NB) {
    const float T = Tfull[t];
    const float var = T * T * Mvk2 + 2.f * T * E * Mvkvb + E * E * Mvb2;
    const float rs = rsqrtf(var + EPSV);
    aSl[t] = T * rs;
    cSl[t] = E * rs;
  }
  __syncthreads();
  const float Uv = U[t], Vv = V[t];
  const float base = b3[t] + Wc[t];
  for (int b = 0; b < NB; ++b)
    out[(size_t)b * NO + t] = fmaf(aSl[b], Uv, fmaf(cSl[b], Vv, base));
}

// =============== K3: combineA -> featP [128][1024] packed (c1 | c3) ===============
__global__ __launch_bounds__(512) void k3_combineA(
    const float* __restrict__ pA, const float* __restrict__ b1,
    u32* __restrict__ featP) {
  const int b = blockIdx.x, t = threadIdx.x;
  const size_t off = (size_t)b * NO + t;
  float d1 = 0.f, d2 = 0.f, d3 = 0.f, d4 = 0.f;
#pragma unroll
  for (int s = 0; s < 8; ++s) {
    d1 += pA[(size_t)(0 * 8 + s) * (NB * NO) + off];
    d2 += pA[(size_t)(1 * 8 + s) * (NB * NO) + off];
    d3 += pA[(size_t)(2 * 8 + s) * (NB * NO) + off];
    d4 += pA[(size_t)(3 * 8 + s) * (NB * NO) + off];
  }
  const float c1v = d1 + b1[t];
  const float gg = sig_fast(d2);
  const float sh = sinh_fast(d4);
  const float c3v = fmaf(gg, d3 - sh, sh);
  u16 h, l;
  bf16_split(c1v, h, l);
  featP[(size_t)b * ND + t] = ((u32)h << 16) | l;
  bf16_split(c3v, h, l);
  featP[(size_t)b * ND + NO + t] = ((u32)h << 16) | l;
}

// =============== K4: gemmB feat[128,1024] @ k3[0:1024,512], atomicAdd into out ===============
__global__ __launch_bounds__(512) void k4_gemmB(
    const u32* __restrict__ featP, const float* __restrict__ k3w,
    float* __restrict__ out) {
  __shared__ __align__(16) char smem[49152];
  const int ks = blockIdx.x >> 3, ot = blockIdx.x & 7;
  gemm_128x64<0, 1>(featP, k3w, nullptr, out, ot * 64, ks * 128, smem);
}

extern "C" void kernel_launch(void* const* d_in, const int* in_sizes, int n_in,
                              void* d_out, int out_size, void* d_ws, size_t ws_size,
                              hipStream_t stream) {
  const float* x    = (const float*)d_in[0];
  const float* gt   = (const float*)d_in[1];
  const float* wt   = (const float*)d_in[2];
  const float* mt   = (const float*)d_in[3];
  const float* k1   = (const float*)d_in[4];
  const float* b1   = (const float*)d_in[5];
  const float* k3   = (const float*)d_in[6];
  const float* b3   = (const float*)d_in[7];
  const float* embk = (const float*)d_in[8];
  const float* embb = (const float*)d_in[9];
  const float* ekd  = (const float*)d_in[10];
  const float* ng   = (const float*)d_in[11];
  const float* nb   = (const float*)d_in[12];

  char* wsb = (char*)d_ws;
  float* Tfull = (float*)wsb;                        // 512 B
  float* U  = (float*)(wsb + 4096);                  // 2 KB each
  float* V  = (float*)(wsb + 8192);
  float* Wc = (float*)(wsb + 12288);
  u32* xP   = (u32*)(wsb + (1u << 20));              // 512 KB
  u32* axP  = (u32*)(wsb + (1u << 20) + (512u << 10));
  u32* waP  = (u32*)(wsb + (2u << 20));              // 2 MB
  float* pA = (float*)(wsb + (4u << 20));            // 32*128*512*4 = 8 MB
  u32* featP = (u32*)(wsb + (12u << 20));            // 512 KB
  float* out = (float*)d_out;

  hipLaunchKernelGGL(k1_misc, dim3(328), dim3(512), 0, stream,
                     x, wt, mt, embk, embb, ekd, k3, ng, nb,
                     Tfull, xP, axP, waP, U, V, Wc);
  hipLaunchKernelGGL(k2_gemmA, dim3(257), dim3(512), 0, stream,
                     xP, axP, waP, k1, gt, embk, embb, ekd, Tfull,
                     U, V, Wc, b3, pA, out);
  hipLaunchKernelGGL(k3_combineA, dim3(128), dim3(512), 0, stream,
                     pA, b1, featP);
  hipLaunchKernelGGL(k4_gemmB, dim3(64), dim3(512), 0, stream,
                     featP, k3, out);
}